// Round 3
// baseline (278.456 us; speedup 1.0000x reference)
//
#include <hip/hip_runtime.h>
#include <math.h>

#define EPSF 1e-8f
#define LAMBDA_C 0.5f

constexpr int Bb = 8;
constexpr int Nn = 32768;
constexpr int Kk = 64;
constexpr int Dd = 64;
constexpr int NW = 32;     // n handled per wave
constexpr int GROUP = 16;  // transpose tile width (n per LDS tile)
constexpr int PAD = 17;    // LDS row stride in floats (conflict-free writes)

// lane <-> k structure: each lane holds slot row k=lane in VGPRs for its
// whole lifetime (no per-iteration operand streaming). Feature row for the
// current n is wave-uniform -> s_load into SGPRs (SMEM pipe, off VALU).
// Softmax over k = cross-lane butterfly; logits <= +0.5 so exp can't
// overflow -> no max pass. Output transposed through a per-wave LDS tile
// for 64B-coalesced stores.
__global__ __launch_bounds__(256, 4) void attn_kernel(
    const float* __restrict__ features,
    const float* __restrict__ slots,
    const float* __restrict__ horizons,
    float* __restrict__ out)
{
    __shared__ float tile[4][Kk * PAD];       // 4 waves x 4352 B
    const int tid  = threadIdx.x;
    const int lane = tid & 63;
    const int wid  = tid >> 6;
    const int w    = blockIdx.x * 4 + wid;    // 8192 waves total
    const int b    = w >> 10;                 // 1024 waves per batch
    const int n0   = (w & 1023) * NW;

    // Slot row for k = lane, resident in 64 VGPRs. Loaded once.
    float sarr[Dd];
    {
        const float4* srow = (const float4*)(slots + (size_t)(b * Kk + lane) * Dd);
        #pragma unroll
        for (int i = 0; i < Dd / 4; ++i) {
            float4 v = srow[i];
            sarr[4*i+0] = v.x; sarr[4*i+1] = v.y;
            sarr[4*i+2] = v.z; sarr[4*i+3] = v.w;
        }
    }
    const float st = sarr[0];
    const float rh = 1.0f / (horizons[b * Kk + lane] + EPSF);
    float* tl = tile[wid];

    #pragma unroll 1
    for (int g = 0; g < NW / GROUP; ++g) {
        const int ng = n0 + g * GROUP;

        #pragma unroll 1
        for (int t = 0; t < GROUP; ++t) {
            const int n = ng + t;
            const float* fp = features + (((size_t)(b << 15) + n) << 6);
            // Difference-form Minkowski: w2 = sum over ALL 64 dims of
            // (f-s)^2; spatial dx2 = w2 - dt^2. No fs2/ss2 needed, and
            // better conditioned than norms-minus-2*cross.
            float a0 = 0.f, a1 = 0.f, a2 = 0.f, a3 = 0.f;
            #pragma unroll
            for (int d = 0; d < Dd; d += 4) {
                float d0 = fp[d+0] - sarr[d+0];   // fp[d]: SGPR operand
                float d1 = fp[d+1] - sarr[d+1];
                float d2 = fp[d+2] - sarr[d+2];
                float d3 = fp[d+3] - sarr[d+3];
                a0 = fmaf(d0, d0, a0); a1 = fmaf(d1, d1, a1);
                a2 = fmaf(d2, d2, a2); a3 = fmaf(d3, d3, a3);
            }
            float w2  = (a0 + a1) + (a2 + a3);
            float dt  = fp[0] - st;
            float dt2 = dt * dt;
            float dx2 = fmaxf(w2 - dt2, 0.0f);
            float interval = dt2 - dx2;
            float adist = sqrtf(fabsf(interval) + EPSF);   // |dist|
            float cone  = (fabsf(dt) - sqrtf(dx2 + EPSF)) * rh;
            float e  = __expf(2.0f * cone);                 // tanh, NaN-free
            float th = 1.0f - 2.0f * __builtin_amdgcn_rcpf(e + 1.0f);
            float logit = fmaf(LAMBDA_C, th, -adist);       // <= +0.5 always
            float p = __expf(logit);                        // no overflow
            // Sum over all 64 k (= lanes): butterfly.
            float s = p;
            #pragma unroll
            for (int m = 32; m >= 1; m >>= 1)
                s += __shfl_xor(s, m, 64);
            tl[lane * PAD + t] = p * __builtin_amdgcn_rcpf(s);
        }

        __syncthreads();   // make tile writes visible (ordering safety)

        // Transposed store: lane -> (k = lane>>2 + 16j, n-quad = lane&3).
        // 4 consecutive lanes emit 64 contiguous bytes of one k-row.
        #pragma unroll
        for (int j = 0; j < 4; ++j) {
            int k  = (lane >> 2) + j * 16;
            int c0 = (lane & 3) * 4;
            float4 v;
            v.x = tl[k * PAD + c0 + 0];
            v.y = tl[k * PAD + c0 + 1];
            v.z = tl[k * PAD + c0 + 2];
            v.w = tl[k * PAD + c0 + 3];
            *(float4*)(out + (((size_t)(b * Kk + k)) << 15) + ng + c0) = v;
        }
        __syncthreads();   // protect tile before next group's writes
    }
}

extern "C" void kernel_launch(void* const* d_in, const int* in_sizes, int n_in,
                              void* d_out, int out_size, void* d_ws, size_t ws_size,
                              hipStream_t stream) {
    const float* features = (const float*)d_in[0];
    const float* slots    = (const float*)d_in[1];
    const float* horizons = (const float*)d_in[2];
    float* out = (float*)d_out;

    // 8192 waves = 2048 blocks of 256 (4 waves each); 8 blocks/CU of work.
    hipLaunchKernelGGL(attn_kernel, dim3(2048), dim3(256), 0, stream,
                       features, slots, horizons, out);
}

// Round 6
// 142.705 us; speedup vs baseline: 1.9513x; 1.9513x over previous
//
#include <hip/hip_runtime.h>
#include <math.h>

#define EPSF 1e-8f

typedef _Float16 f16x8 __attribute__((ext_vector_type(8)));
typedef float    f32x4 __attribute__((ext_vector_type(4)));

constexpr int Bb = 8, Nn = 32768, Kk = 64, Dd = 64;

// GEMM-ified: C[k][n] = sum_d slots[k][d] * features[n][d] via
// v_mfma_f32_16x16x32_f16 with fp32 operands split hi/lo into f16
// (3 products: hi*hi + hi*lo + lo*hi ~ fp32-accurate; bf16 split would
// fail the sqrt-amplified threshold near the light cone).
// A = slots (rows k, resident in VGPRs, d0 zeroed -> spatial cross term
// directly). B = features (cols n, per-tile). C layout: col=lane&15=n,
// row=quad*4+reg=k  =>  softmax over k = local sum + 2 shuffles, and
// stores are 64B-contiguous per k-row (no LDS transpose).
__global__ __launch_bounds__(256, 3) void attn_kernel(
    const float* __restrict__ features,
    const float* __restrict__ slots,
    const float* __restrict__ horizons,
    float* __restrict__ out)
{
    __shared__ float s_st[Kk], s_ss2[Kk], s_rh[Kk];

    const int tid  = threadIdx.x;
    const int bid  = blockIdx.x;
    const int b    = bid >> 7;        // 128 blocks per batch
    const int blk  = bid & 127;
    const int lane = tid & 63;
    const int wid  = tid >> 6;
    const int m    = lane & 15;       // MFMA row/col lane index
    const int quad = lane >> 4;

    // ---- per-block slot constants: st[k], spatial ss2[k], 1/(h+eps) ----
    if (tid < Kk) {
        const float4* sr = (const float4*)(slots + (size_t)(b * Kk + tid) * Dd);
        float4 v = sr[0];
        float st = v.x;
        float ss = v.y * v.y + v.z * v.z + v.w * v.w;   // exclude d0
        #pragma unroll
        for (int i = 1; i < 16; ++i) {
            float4 u = sr[i];
            ss += u.x * u.x + u.y * u.y + u.z * u.z + u.w * u.w;
        }
        s_st[tid]  = st;
        s_ss2[tid] = ss;
        s_rh[tid]  = 1.0f / (horizons[b * Kk + tid] + EPSF);
    }

    // ---- A fragments (slots), loaded once per wave, hi/lo split ----
    // A[mrow = lane&15][kdim = quad*8+j], row-tile t covers k = 16t..16t+15,
    // d-chunk c covers d = 32c..32c+31. d==0 zeroed (time dim out of dot).
    f16x8 a_hi[4][2], a_lo[4][2];
    #pragma unroll
    for (int t = 0; t < 4; ++t) {
        #pragma unroll
        for (int c = 0; c < 2; ++c) {
            const float* sp = slots + (size_t)(b * Kk + 16 * t + m) * Dd
                            + 32 * c + quad * 8;
            float4 u0 = *(const float4*)sp;
            float4 u1 = *(const float4*)(sp + 4);
            float fv[8] = {u0.x, u0.y, u0.z, u0.w, u1.x, u1.y, u1.z, u1.w};
            if (c == 0 && quad == 0) fv[0] = 0.0f;
            #pragma unroll
            for (int j = 0; j < 8; ++j) {
                float x = fv[j];
                _Float16 h = (_Float16)x;              // RN split
                _Float16 l = (_Float16)(x - (float)h);
                a_hi[t][c][j] = h;
                a_lo[t][c][j] = l;
            }
        }
    }
    __syncthreads();

    #pragma unroll 1
    for (int it = 0; it < 4; ++it) {
        const int n0 = (blk * 16 + wid * 4 + it) * 16;

        // B fragments (features) for this 16-n tile + fs2 partials.
        f16x8 b_hi[2], b_lo[2];
        float f00 = 0.f, fs2p = 0.f;
        #pragma unroll
        for (int c = 0; c < 2; ++c) {
            const float* fp = features + (((size_t)b << 15) + n0 + m) * Dd
                            + 32 * c + quad * 8;
            float4 u0 = *(const float4*)fp;
            float4 u1 = *(const float4*)(fp + 4);
            float fv[8] = {u0.x, u0.y, u0.z, u0.w, u1.x, u1.y, u1.z, u1.w};
            if (c == 0) f00 = fv[0];      // quad==0 lanes hold f[n][0]
            #pragma unroll
            for (int j = 0; j < 8; ++j) {
                float x = fv[j];
                fs2p = fmaf(x, x, fs2p);
                _Float16 h = (_Float16)x;
                _Float16 l = (_Float16)(x - (float)h);
                b_hi[c][j] = h;
                b_lo[c][j] = l;
            }
        }
        const float ft = __shfl(f00, m);         // lane m (<16, quad 0)
        float fs2 = fs2p;
        fs2 += __shfl_xor(fs2, 16);
        fs2 += __shfl_xor(fs2, 32);              // full |f|^2 over 64 d
        fs2 = fmaf(-ft, ft, fs2);                // spatial only

        // ---- 24 MFMAs: 4 k-row-tiles x 2 d-chunks x 3 split products ----
        f32x4 acc[4];
        #pragma unroll
        for (int t = 0; t < 4; ++t) {
            f32x4 a = {0.f, 0.f, 0.f, 0.f};
            #pragma unroll
            for (int c = 0; c < 2; ++c) {
                a = __builtin_amdgcn_mfma_f32_16x16x32_f16(a_hi[t][c], b_hi[c], a, 0, 0, 0);
                a = __builtin_amdgcn_mfma_f32_16x16x32_f16(a_hi[t][c], b_lo[c], a, 0, 0, 0);
                a = __builtin_amdgcn_mfma_f32_16x16x32_f16(a_lo[t][c], b_hi[c], a, 0, 0, 0);
            }
            acc[t] = a;
        }

        // ---- epilogue: logits -> p, running sum over k ----
        float p[4][4];
        float sum = 0.f;
        #pragma unroll
        for (int t = 0; t < 4; ++t) {
            #pragma unroll
            for (int r = 0; r < 4; ++r) {
                const int k = 16 * t + quad * 4 + r;   // C row
                float st  = s_st[k];                   // distinct banks/quad
                float ss2 = s_ss2[k];
                float rh  = s_rh[k];
                float cross = acc[t][r];               // spatial dot
                float dt  = ft - st;
                float dx2 = fmaf(-2.f, cross, fs2 + ss2);
                dx2 = fmaxf(dx2, 0.f);
                float interval = fmaf(dt, dt, -dx2);
                float adist = __builtin_amdgcn_sqrtf(fabsf(interval) + EPSF);
                float cone  = (fabsf(dt) - __builtin_amdgcn_sqrtf(dx2 + EPSF)) * rh;
                float e  = __expf(2.0f * cone);        // tanh via exp, NaN-free
                float th = 1.0f - 2.0f * __builtin_amdgcn_rcpf(e + 1.0f);
                float logit = fmaf(0.5f, th, -adist);  // <= +0.5: exp safe
                float pe = __expf(logit);
                p[t][r] = pe;
                sum += pe;
            }
        }
        sum += __shfl_xor(sum, 16);
        sum += __shfl_xor(sum, 32);                    // total over 64 k
        const float inv = __builtin_amdgcn_rcpf(sum);

        // ---- stores: per (t,r) instr writes 4 k-rows x 64B contiguous ----
        float* ob = out + (((size_t)(b * Kk)) << 15) + n0 + m;
        #pragma unroll
        for (int t = 0; t < 4; ++t) {
            #pragma unroll
            for (int r = 0; r < 4; ++r) {
                const int k = 16 * t + quad * 4 + r;
                ob[(size_t)k << 15] = p[t][r] * inv;
            }
        }
    }
}

extern "C" void kernel_launch(void* const* d_in, const int* in_sizes, int n_in,
                              void* d_out, int out_size, void* d_ws, size_t ws_size,
                              hipStream_t stream) {
    const float* features = (const float*)d_in[0];
    const float* slots    = (const float*)d_in[1];
    const float* horizons = (const float*)d_in[2];
    float* out = (float*)d_out;

    // 1024 blocks x 256 thr = 4096 waves; each wave: 4 tiles of 16 n.
    hipLaunchKernelGGL(attn_kernel, dim3(1024), dim3(256), 0, stream,
                       features, slots, horizons, out);
}